// Round 4
// baseline (591.830 us; speedup 1.0000x reference)
//
#include <hip/hip_runtime.h>
#include <math.h>

#define NBATCH 64
#define Q      1000
#define C      1203
#define QC     1203000         // Q*C
#define QC4    300750          // QC/4 (QC % 4 == 0)
#define QC4TOT (NBATCH*QC4)    // 19,248,000 float4s total
#define K      100
#define NBINS  2048            // fallback histogram bins (top 11 bits of mono key)
#define CAP    2048            // candidate slots per batch
#define BS     256
#define GRID   4096            // scan blocks (grid-stride)
#define TLOGIT 3.4f            // exp ~405 hits/batch for N(0,1); 15 sigma above K=100

// monotonic uint key: key increasing <=> float increasing; ties -> lower index first
__device__ __forceinline__ unsigned int mono_key(float x) {
    unsigned int u = __float_as_uint(x);
    return u ^ ((u >> 31) ? 0xFFFFFFFFu : 0x80000000u);
}
__device__ __forceinline__ float key_to_float(unsigned int k) {
    unsigned int u = (k & 0x80000000u) ? (k ^ 0x80000000u) : ~k;
    return __uint_as_float(u);
}

// Single full read of logits, simplest possible streaming shape.
// Hot loop: load float4 -> 3 fmax + 1 cmp. Rare (1 in ~3000 elements) slow path.
__global__ void __launch_bounds__(BS) scan_kernel(const float4* __restrict__ src,
                                                  unsigned int* __restrict__ cnt,
                                                  uint2* __restrict__ cand) {
    const int stride = GRID * BS;
    for (int i = blockIdx.x * BS + threadIdx.x; i < QC4TOT; i += stride) {
        float4 v = src[i];
        float m = fmaxf(fmaxf(v.x, v.y), fmaxf(v.z, v.w));
        if (m >= TLOGIT) {
            int b = i / QC4;                       // constant div -> mulhi
            unsigned int e = (unsigned int)(i - b * QC4) * 4u;
            uint2* cb = cand + (size_t)b * CAP;
            if (v.x >= TLOGIT) { unsigned int s = atomicAdd(&cnt[b], 1u); if (s < CAP) cb[s] = make_uint2(mono_key(v.x), e + 0u); }
            if (v.y >= TLOGIT) { unsigned int s = atomicAdd(&cnt[b], 1u); if (s < CAP) cb[s] = make_uint2(mono_key(v.y), e + 1u); }
            if (v.z >= TLOGIT) { unsigned int s = atomicAdd(&cnt[b], 1u); if (s < CAP) cb[s] = make_uint2(mono_key(v.z), e + 2u); }
            if (v.w >= TLOGIT) { unsigned int s = atomicAdd(&cnt[b], 1u); if (s < CAP) cb[s] = make_uint2(mono_key(v.w), e + 3u); }
        }
    }
}

// One block per batch: validate fast path, gather candidates, exact rank
// (key desc, idx asc), write scores/labels/boxes. Exact in-block histogram
// fallback if the fixed threshold failed for this batch (never fires for
// N(0,1) logits; kept for unconditional correctness).
__global__ void __launch_bounds__(BS) finish_kernel(const unsigned int* __restrict__ cnt,
                                                    const uint2* __restrict__ cand,
                                                    const float* __restrict__ logits,
                                                    const float* __restrict__ bbox,
                                                    const float* __restrict__ tsizes,
                                                    float* __restrict__ out) {
    __shared__ uint2 sc[CAP];
    __shared__ unsigned int lh[NBINS];
    __shared__ unsigned int sn;
    int b = blockIdx.x;
    unsigned int n = cnt[b];
    bool fast = (n >= (unsigned int)K && n <= (unsigned int)CAP);

    if (fast) {
        const uint2* cb = cand + (size_t)b * CAP;
        for (unsigned int i = threadIdx.x; i < n; i += BS) sc[i] = cb[i];
        __syncthreads();
    } else {
        // exact fallback: histogram threshold + collect, all within this block
        for (int i = threadIdx.x; i < NBINS; i += BS) lh[i] = 0u;
        __syncthreads();
        const float4* src = (const float4*)(logits + (size_t)b * QC);
        for (int i = threadIdx.x; i < QC4; i += BS) {
            float4 v = src[i];
            atomicAdd(&lh[mono_key(v.x) >> 21], 1u);
            atomicAdd(&lh[mono_key(v.y) >> 21], 1u);
            atomicAdd(&lh[mono_key(v.z) >> 21], 1u);
            atomicAdd(&lh[mono_key(v.w) >> 21], 1u);
        }
        __syncthreads();
        if (threadIdx.x == 0) {
            unsigned int cum = 0; int tb = 0;
            for (int i = NBINS - 1; i >= 0; --i) { cum += lh[i]; if (cum >= (unsigned int)K) { tb = i; break; } }
            lh[0] = ((unsigned int)tb) << 21;   // reuse as threshold broadcast
            sn = 0u;
        }
        __syncthreads();
        unsigned int tk = lh[0];
        for (int i = threadIdx.x; i < QC4; i += BS) {
            float4 v = src[i];
            unsigned int e = 4u * (unsigned int)i;
            unsigned int k0 = mono_key(v.x), k1 = mono_key(v.y), k2 = mono_key(v.z), k3 = mono_key(v.w);
            if (k0 >= tk) { unsigned int s = atomicAdd(&sn, 1u); if (s < CAP) sc[s] = make_uint2(k0, e + 0u); }
            if (k1 >= tk) { unsigned int s = atomicAdd(&sn, 1u); if (s < CAP) sc[s] = make_uint2(k1, e + 1u); }
            if (k2 >= tk) { unsigned int s = atomicAdd(&sn, 1u); if (s < CAP) sc[s] = make_uint2(k2, e + 2u); }
            if (k3 >= tk) { unsigned int s = atomicAdd(&sn, 1u); if (s < CAP) sc[s] = make_uint2(k3, e + 3u); }
        }
        __syncthreads();
        n = sn < (unsigned int)CAP ? sn : (unsigned int)CAP;
    }

    float img_h = tsizes[2 * b + 0];
    float img_w = tsizes[2 * b + 1];
    float* scores = out;
    float* labels = out + NBATCH * K;
    float* boxes  = out + 2 * NBATCH * K;
    for (unsigned int i = threadIdx.x; i < n; i += BS) {
        uint2 me = sc[i];
        int rank = 0;
        for (unsigned int j = 0; j < n; ++j) {
            uint2 o = sc[j];
            if (o.x > me.x || (o.x == me.x && o.y < me.y)) rank++;
        }
        if (rank < K) {
            float v = key_to_float(me.x);
            double sd = 1.0 / (1.0 + exp(-(double)v));
            scores[b * K + rank] = (float)sd;
            unsigned int idx = me.y;
            unsigned int q   = idx / C;
            unsigned int lab = idx - q * C;
            labels[b * K + rank] = (float)lab;
            const float* bb = bbox + ((size_t)b * Q + q) * 4;
            float cx = bb[0], cy = bb[1], w = bb[2], h = bb[3];
            float* o = boxes + ((size_t)b * K + (size_t)rank) * 4;
            o[0] = (cx - 0.5f * w) * img_w;
            o[1] = (cy - 0.5f * h) * img_h;
            o[2] = (cx + 0.5f * w) * img_w;
            o[3] = (cy + 0.5f * h) * img_h;
        }
    }
}

extern "C" void kernel_launch(void* const* d_in, const int* in_sizes, int n_in,
                              void* d_out, int out_size, void* d_ws, size_t ws_size,
                              hipStream_t stream) {
    const float* logits = (const float*)d_in[0];   // 64*1000*1203 f32
    const float* bbox   = (const float*)d_in[1];   // 64*1000*4 f32
    const float* tsizes = (const float*)d_in[2];   // 64*2 f32
    float* out = (float*)d_out;                    // [scores 6400 | labels 6400 | boxes 25600]

    char* ws = (char*)d_ws;
    unsigned int* cnt  = (unsigned int*)(ws);      // 64*4 = 256 B
    uint2*        cand = (uint2*)(ws + 256);       // 64*2048*8 = 1 MiB

    hipMemsetAsync(cnt, 0, NBATCH * sizeof(unsigned int), stream);
    scan_kernel<<<GRID, BS, 0, stream>>>((const float4*)logits, cnt, cand);
    finish_kernel<<<NBATCH, BS, 0, stream>>>(cnt, cand, logits, bbox, tsizes, out);
}

// Round 5
// 550.825 us; speedup vs baseline: 1.0744x; 1.0744x over previous
//
#include <hip/hip_runtime.h>
#include <math.h>

#define NBATCH 64
#define Q      1000
#define C      1203
#define QC     1203000         // Q*C
#define QC4    300750          // QC/4 (QC % 4 == 0)
#define QC4TOT (NBATCH*QC4)    // 19,248,000 float4s total
#define K      100
#define NBINS  2048            // fallback histogram bins (top 11 bits of mono key)
#define CAP    2048            // candidate slots per batch
#define BS     256
#define U      8               // independent float4 loads in flight per thread
#define TILE   (BS*U)          // 2048 float4s per block-iteration
#define NTILES ((QC4TOT + TILE - 1) / TILE)   // 9399 (last tile partial: 896)
#define GRID   2048            // scan blocks (grid-stride over tiles)
#define TLOGIT 3.4f            // exp ~405 hits/batch for N(0,1); 15 sigma above K=100

// monotonic uint key: key increasing <=> float increasing; ties -> lower index first
__device__ __forceinline__ unsigned int mono_key(float x) {
    unsigned int u = __float_as_uint(x);
    return u ^ ((u >> 31) ? 0xFFFFFFFFu : 0x80000000u);
}
__device__ __forceinline__ float key_to_float(unsigned int k) {
    unsigned int u = (k & 0x80000000u) ? (k ^ 0x80000000u) : ~k;
    return __uint_as_float(u);
}
__device__ __forceinline__ float max4(float4 v) {
    return fmaxf(fmaxf(v.x, v.y), fmaxf(v.z, v.w));
}

// Single full read of logits. 8 independent dwordx4 loads issued back-to-back
// per thread per tile (8 KB in flight per wave) to cover HBM latency.
// Rare path (per-256-element wave granule, ~8% taken) collects candidates.
__global__ void __launch_bounds__(BS) scan_kernel(const float4* __restrict__ src,
                                                  unsigned int* __restrict__ cnt,
                                                  uint2* __restrict__ cand) {
    for (int t = blockIdx.x; t < NTILES; t += GRID) {
        int base = t * TILE + (int)threadIdx.x;
        float4 v[U];
        if (t < NTILES - 1) {
            #pragma unroll
            for (int u = 0; u < U; ++u) v[u] = src[base + u * BS];
        } else {
            #pragma unroll
            for (int u = 0; u < U; ++u) {
                int idx = base + u * BS;
                v[u] = (idx < QC4TOT) ? src[idx]
                                      : make_float4(-1e30f, -1e30f, -1e30f, -1e30f);
            }
        }
        #pragma unroll
        for (int u = 0; u < U; ++u) {
            if (max4(v[u]) >= TLOGIT) {          // rare: ~8% of wave-granules
                int idx = base + u * BS;         // float4 index, valid (filler never passes)
                int b = idx / QC4;               // constant div -> mulhi
                unsigned int e = (unsigned int)(idx - b * QC4) * 4u;
                uint2* cb = cand + (size_t)b * CAP;
                if (v[u].x >= TLOGIT) { unsigned int s = atomicAdd(&cnt[b], 1u); if (s < CAP) cb[s] = make_uint2(mono_key(v[u].x), e + 0u); }
                if (v[u].y >= TLOGIT) { unsigned int s = atomicAdd(&cnt[b], 1u); if (s < CAP) cb[s] = make_uint2(mono_key(v[u].y), e + 1u); }
                if (v[u].z >= TLOGIT) { unsigned int s = atomicAdd(&cnt[b], 1u); if (s < CAP) cb[s] = make_uint2(mono_key(v[u].z), e + 2u); }
                if (v[u].w >= TLOGIT) { unsigned int s = atomicAdd(&cnt[b], 1u); if (s < CAP) cb[s] = make_uint2(mono_key(v[u].w), e + 3u); }
            }
        }
    }
}

// One block per batch: validate fast path, gather candidates, exact rank
// (key desc, idx asc), write scores/labels/boxes. Exact in-block histogram
// fallback if the fixed threshold failed for this batch (never fires for
// N(0,1) logits; kept for unconditional correctness).
__global__ void __launch_bounds__(BS) finish_kernel(const unsigned int* __restrict__ cnt,
                                                    const uint2* __restrict__ cand,
                                                    const float* __restrict__ logits,
                                                    const float* __restrict__ bbox,
                                                    const float* __restrict__ tsizes,
                                                    float* __restrict__ out) {
    __shared__ uint2 sc[CAP];
    __shared__ unsigned int lh[NBINS];
    __shared__ unsigned int sn;
    int b = blockIdx.x;
    unsigned int n = cnt[b];
    bool fast = (n >= (unsigned int)K && n <= (unsigned int)CAP);

    if (fast) {
        const uint2* cb = cand + (size_t)b * CAP;
        for (unsigned int i = threadIdx.x; i < n; i += BS) sc[i] = cb[i];
        __syncthreads();
    } else {
        // exact fallback: histogram threshold + collect, all within this block
        for (int i = threadIdx.x; i < NBINS; i += BS) lh[i] = 0u;
        __syncthreads();
        const float4* src = (const float4*)(logits + (size_t)b * QC);
        for (int i = threadIdx.x; i < QC4; i += BS) {
            float4 v = src[i];
            atomicAdd(&lh[mono_key(v.x) >> 21], 1u);
            atomicAdd(&lh[mono_key(v.y) >> 21], 1u);
            atomicAdd(&lh[mono_key(v.z) >> 21], 1u);
            atomicAdd(&lh[mono_key(v.w) >> 21], 1u);
        }
        __syncthreads();
        if (threadIdx.x == 0) {
            unsigned int cum = 0; int tb = 0;
            for (int i = NBINS - 1; i >= 0; --i) { cum += lh[i]; if (cum >= (unsigned int)K) { tb = i; break; } }
            lh[0] = ((unsigned int)tb) << 21;   // reuse as threshold broadcast
            sn = 0u;
        }
        __syncthreads();
        unsigned int tk = lh[0];
        for (int i = threadIdx.x; i < QC4; i += BS) {
            float4 v = src[i];
            unsigned int e = 4u * (unsigned int)i;
            unsigned int k0 = mono_key(v.x), k1 = mono_key(v.y), k2 = mono_key(v.z), k3 = mono_key(v.w);
            if (k0 >= tk) { unsigned int s = atomicAdd(&sn, 1u); if (s < CAP) sc[s] = make_uint2(k0, e + 0u); }
            if (k1 >= tk) { unsigned int s = atomicAdd(&sn, 1u); if (s < CAP) sc[s] = make_uint2(k1, e + 1u); }
            if (k2 >= tk) { unsigned int s = atomicAdd(&sn, 1u); if (s < CAP) sc[s] = make_uint2(k2, e + 2u); }
            if (k3 >= tk) { unsigned int s = atomicAdd(&sn, 1u); if (s < CAP) sc[s] = make_uint2(k3, e + 3u); }
        }
        __syncthreads();
        n = sn < (unsigned int)CAP ? sn : (unsigned int)CAP;
    }

    float img_h = tsizes[2 * b + 0];
    float img_w = tsizes[2 * b + 1];
    float* scores = out;
    float* labels = out + NBATCH * K;
    float* boxes  = out + 2 * NBATCH * K;
    for (unsigned int i = threadIdx.x; i < n; i += BS) {
        uint2 me = sc[i];
        int rank = 0;
        for (unsigned int j = 0; j < n; ++j) {
            uint2 o = sc[j];
            if (o.x > me.x || (o.x == me.x && o.y < me.y)) rank++;
        }
        if (rank < K) {
            float v = key_to_float(me.x);
            double sd = 1.0 / (1.0 + exp(-(double)v));
            scores[b * K + rank] = (float)sd;
            unsigned int idx = me.y;
            unsigned int q   = idx / C;
            unsigned int lab = idx - q * C;
            labels[b * K + rank] = (float)lab;
            const float* bb = bbox + ((size_t)b * Q + q) * 4;
            float cx = bb[0], cy = bb[1], w = bb[2], h = bb[3];
            float* o = boxes + ((size_t)b * K + (size_t)rank) * 4;
            o[0] = (cx - 0.5f * w) * img_w;
            o[1] = (cy - 0.5f * h) * img_h;
            o[2] = (cx + 0.5f * w) * img_w;
            o[3] = (cy + 0.5f * h) * img_h;
        }
    }
}

extern "C" void kernel_launch(void* const* d_in, const int* in_sizes, int n_in,
                              void* d_out, int out_size, void* d_ws, size_t ws_size,
                              hipStream_t stream) {
    const float* logits = (const float*)d_in[0];   // 64*1000*1203 f32
    const float* bbox   = (const float*)d_in[1];   // 64*1000*4 f32
    const float* tsizes = (const float*)d_in[2];   // 64*2 f32
    float* out = (float*)d_out;                    // [scores 6400 | labels 6400 | boxes 25600]

    char* ws = (char*)d_ws;
    unsigned int* cnt  = (unsigned int*)(ws);      // 64*4 = 256 B
    uint2*        cand = (uint2*)(ws + 256);       // 64*2048*8 = 1 MiB

    hipMemsetAsync(cnt, 0, NBATCH * sizeof(unsigned int), stream);
    scan_kernel<<<GRID, BS, 0, stream>>>((const float4*)logits, cnt, cand);
    finish_kernel<<<NBATCH, BS, 0, stream>>>(cnt, cand, logits, bbox, tsizes, out);
}